// Round 2
// baseline (163.733 us; speedup 1.0000x reference)
//
#include <hip/hip_runtime.h>
#include <math.h>

#define VOCAB  50000
#define D_EMB  300
#define NBINS  11
#define BATCH  64
#define LQ     32
#define LD     1024
#define NSTEP  10             // K padded to 320 = 10 * 32 (MFMA K=32 steps)

// ---- main-path geometry: 32 doc tokens per block ----
#define DT2    32
#define NDT2   (LD / DT2)     // 32
// fallback geometry (old kernel)
#define DTILE  64
#define NDT    (LD / DTILE)   // 16

// ---- workspace layout (main path) ----
// [0, 2.88MB)        partial [dt][b][q][k] f32
// [2.88MB, +1.31MB)  qtab: per (b,qt) fragment-linear bf16 region (10,240 B each)
// [4 MiB, +8KB)      invq per query instance (from ROUNDED values)
#define PARTIAL2_BYTES ((size_t)NDT2 * BATCH * LQ * NBINS * 4)   // 2,883,584
#define QTAB_OFF       PARTIAL2_BYTES
#define QTAB_BYTES     ((size_t)BATCH * 2 * NSTEP * 512 * 2)     // 1,310,720
#define INVQ_OFF       ((size_t)4194304)                         // 4 MiB, 16-aligned
#define WS_NEED2       (INVQ_OFF + (size_t)BATCH * LQ * 4)       // 4,202,496

typedef __attribute__((ext_vector_type(8))) short short8;          // 8 bf16
typedef __attribute__((ext_vector_type(4))) float floatx4;         // MFMA C/D
typedef unsigned int u32;

__constant__ float c_mu[NBINS]  = {1.0f, 0.9f, 0.7f, 0.5f, 0.3f, 0.1f,
                                   -0.1f, -0.3f, -0.5f, -0.7f, -0.9f};
// 1 / (2*sigma^2): sigma=1e-3 -> 5e5 ; sigma=0.1 -> 50
__constant__ float c_is2[NBINS] = {500000.0f, 50.f, 50.f, 50.f, 50.f, 50.f,
                                   50.f, 50.f, 50.f, 50.f, 50.f};

static __device__ __forceinline__ unsigned short f32_bf16(float f) {
  unsigned u = __float_as_uint(f);
  u += 0x7FFFu + ((u >> 16) & 1u);          // RNE
  return (unsigned short)(u >> 16);
}
static __device__ __forceinline__ float bf16_f32(unsigned short h) {
  return __uint_as_float(((unsigned)h) << 16);
}

// async global->LDS: 64 lanes x 16 B, LDS dest = uniform base + lane*16
static __device__ __forceinline__ void gload_lds16(const void* g, void* l) {
  __builtin_amdgcn_global_load_lds(
      (__attribute__((address_space(1))) u32*)g,
      (__attribute__((address_space(3))) u32*)l, 16, 0, 0);
}

// ---------------------------------------------------------------------------
// qprep: convert the 2048 query INSTANCES (not the vocab) to fragment-linear
// bf16 regions + per-instance inv-norms from ROUNDED values. One wave per
// instance; lane m<40 owns elems 8m..8m+7 (fully coalesced 32 B reads).
__global__ __launch_bounds__(256) void knrm_qprep(
    const int* __restrict__ inputs_q, const float* __restrict__ word_emb,
    unsigned short* __restrict__ qtab, float* __restrict__ invq)
{
  const int wid  = threadIdx.x >> 6;
  const int lane = threadIdx.x & 63;
  const int qi   = blockIdx.x * 4 + wid;          // 0..2047
  const int tok  = inputs_q[qi];
  const int b    = qi >> 5, q = qi & 31;
  const int rl   = q & 15, qt = q >> 4;

  const float4* src = (const float4*)(word_emb + (size_t)tok * D_EMB); // 75 f4
  float4 fa = make_float4(0.f, 0.f, 0.f, 0.f);
  float4 fb = make_float4(0.f, 0.f, 0.f, 0.f);
  if (lane < 38) fa = src[2 * lane];          // k = 8m..8m+3  (m=37 -> 296..299)
  if (lane < 37) fb = src[2 * lane + 1];      // k = 8m+4..8m+7 (m=36 -> 292..295)

  unsigned short h[8];
  h[0] = f32_bf16(fa.x); h[1] = f32_bf16(fa.y);
  h[2] = f32_bf16(fa.z); h[3] = f32_bf16(fa.w);
  h[4] = f32_bf16(fb.x); h[5] = f32_bf16(fb.y);
  h[6] = f32_bf16(fb.z); h[7] = f32_bf16(fb.w);
  float p = 0.f;
  short8 v;
#pragma unroll
  for (int j = 0; j < 8; ++j) {
    const float x = bf16_f32(h[j]);
    p += x * x;
    v[j] = (short)h[j];
  }
#pragma unroll
  for (int off = 1; off < 64; off <<= 1) p += __shfl_xor(p, off);
  if (lane == 0) invq[qi] = 1.f / fmaxf(sqrtf(p), 1e-12f);

  if (lane < 40) {                              // s = m>>2, khi = m&3
    const int s = lane >> 2, khi = lane & 3;
    *(short8*)(qtab + ((size_t)(b * 2 + qt)) * (NSTEP * 512)
                    + s * 512 + (khi * 16 + rl) * 8) = v;
  }
}

// ---------------------------------------------------------------------------
// Main: one block = (batch b, 32-doc-token tile). Doc rows DMA'd as raw f32
// (source pre-swizzled for bank-free LDS reads), converted per-wave into
// REGISTER B-fragments; q fragments DMA'd from qtab; norms in-register.
__global__ __launch_bounds__(256) void knrm_main2(
    const int* __restrict__ inputs_d, const float* __restrict__ mask_d,
    const float* __restrict__ word_emb, const unsigned short* __restrict__ qtab,
    const float* __restrict__ invq, float* __restrict__ partial)
{
  const int b    = blockIdx.y;
  const int dt   = blockIdx.x;                  // 0..31
  const int tid  = threadIdx.x;
  const int wid  = tid >> 6;
  const int lane = tid & 63;
  const int khi  = lane >> 4;   // 0..3
  const int rl   = lane & 15;   // 0..15

  __shared__ __align__(16) short Afrag[2 * NSTEP * 512];   // 20,480 B
  __shared__ __align__(16) float Dstage[DT2 * 320];        // 40,960 B (1280 B/row)
  __shared__ float invq_s[LQ];
  __shared__ float red[4][16][NBINS];

  const int dbase = b * LD + dt * DT2;

  // ---- d-row staging: 40 flat DMA instrs (10/wave). LDS dest linear; the
  // XOR swizzle ((row&7)<<4) is applied to the per-lane GLOBAL source so the
  // stride-1280 conversion reads below are bank-conflict-free (rule 21).
  {
    char* Dst = (char*)Dstage;
    const char* embb = (const char*)word_emb;
#pragma unroll
    for (int i = 0; i < 10; ++i) {
      const int obase = (wid * 10 + i) * 1024;
      const int o = obase + lane * 16;
      const int r = (o >> 8) / 5;               // o / 1280
      int bo = (o - r * 1280) ^ ((r & 7) << 4); // inverse swizzle on source
      if (bo >= 1200) bo = 0;                   // pad bytes: harmless dup load
      const int tok = inputs_d[dbase + r];
      gload_lds16(embb + (size_t)tok * 1200 + bo, Dst + obase);
    }
  }
  // ---- q fragment staging: 20 linear DMA instrs (5/wave) from qtab
  {
    const char* qsrc = (const char*)(qtab + (size_t)b * 2 * (NSTEP * 512));
    char* Adst = (char*)Afrag;
#pragma unroll
    for (int i = 0; i < 5; ++i) {
      const int off = (wid * 5 + i) * 1024;
      gload_lds16(qsrc + off + lane * 16, Adst + off);
    }
  }
  if (tid < LQ) invq_s[tid] = invq[b * LQ + tid];
  __syncthreads();   // drains vmcnt(0): all 61 KB landed

  // ---- per-wave conversion: wave (qt=wid>>1, dp=wid&1) builds register
  // B-fragments for d-rows dp*16..+16 and this row's inv-norm (from ROUNDED).
  const int qt = wid >> 1, dp = wid & 1;
  const int rloc = dp * 16 + rl;
  short8 bfr[NSTEP];
  float p = 0.f;
  {
    const char* rowp = (const char*)Dstage + rloc * 1280;
    const int swz = (rloc & 7) << 4;
#pragma unroll
    for (int s = 0; s < NSTEP; ++s) {
      const int k0 = 32 * s + 8 * khi;
      const int c0 = 4 * k0;
      float4 fa = make_float4(0.f, 0.f, 0.f, 0.f);
      float4 fb = make_float4(0.f, 0.f, 0.f, 0.f);
      if (k0 < D_EMB)     fa = *(const float4*)(rowp + (c0 ^ swz));
      if (k0 + 4 < D_EMB) fb = *(const float4*)(rowp + ((c0 + 16) ^ swz));
      unsigned short h[8];
      h[0] = f32_bf16(fa.x); h[1] = f32_bf16(fa.y);
      h[2] = f32_bf16(fa.z); h[3] = f32_bf16(fa.w);
      h[4] = f32_bf16(fb.x); h[5] = f32_bf16(fb.y);
      h[6] = f32_bf16(fb.z); h[7] = f32_bf16(fb.w);
      short8 v;
#pragma unroll
      for (int j = 0; j < 8; ++j) {
        const float x = bf16_f32(h[j]);
        p += x * x;
        v[j] = (short)h[j];
      }
      bfr[s] = v;
    }
  }
  p += __shfl_xor(p, 16); p += __shfl_xor(p, 32);   // khi-slices -> row sumsq
  const float invd = 1.f / fmaxf(sqrtf(p), 1e-12f);

  // ---- MFMA: A from LDS (qt region), B from registers. 10 steps.
  const short* Ab = Afrag + qt * (NSTEP * 512);
  floatx4 acc = {0.f, 0.f, 0.f, 0.f};
#pragma unroll
  for (int s = 0; s < NSTEP; ++s) {
    const short8 a = *(const short8*)(Ab + s * 512 + lane * 8);
    acc = __builtin_amdgcn_mfma_f32_16x16x32_bf16(a, bfr[s], acc, 0, 0, 0);
  }

  // ---- epilogue: normalize, RBF bins, pool over this wave's 16 d-cols
  float ps[4][NBINS];
#pragma unroll
  for (int r = 0; r < 4; ++r)
#pragma unroll
    for (int k = 0; k < NBINS; ++k) ps[r][k] = 0.f;

  float iq[4];
#pragma unroll
  for (int r = 0; r < 4; ++r) iq[r] = invq_s[16 * qt + 4 * khi + r];

  const float md = mask_d[dbase + rloc];
#pragma unroll
  for (int r = 0; r < 4; ++r) {                 // C/D row = 4*(lane>>4)+r
    const float sv = acc[r] * iq[r] * invd;     // C/D col = lane&15 = rloc
#pragma unroll
    for (int k = 0; k < NBINS; ++k) {
      const float d = sv - c_mu[k];
      ps[r][k] += md * __expf(-d * d * c_is2[k]);
    }
  }

#pragma unroll
  for (int off = 1; off < 16; off <<= 1)
#pragma unroll
    for (int r = 0; r < 4; ++r)
#pragma unroll
      for (int k = 0; k < NBINS; ++k)
        ps[r][k] += __shfl_xor(ps[r][k], off);

  if (rl == 0)
#pragma unroll
    for (int r = 0; r < 4; ++r)
#pragma unroll
      for (int k = 0; k < NBINS; ++k)
        red[wid][4 * khi + r][k] = ps[r][k];
  __syncthreads();

  // partial [dt][b][q][k]: contiguous 1408 B per block
  float* pout = partial + ((size_t)dt * BATCH + b) * (LQ * NBINS);
  for (int v = tid; v < LQ * NBINS; v += 256) {
    const int q = v / NBINS, k = v % NBINS;
    pout[v] = (q < 16) ? (red[0][q][k] + red[1][q][k])
                       : (red[2][q - 16][k] + red[3][q - 16][k]);
  }
}

// ---------------------------------------------------------------------------
// Fallback (proven round-0 kernel, f32 gather + in-kernel conversion) for
// ws_size < WS_NEED2. Writes partial with ndt=16 tiles.
static __device__ __forceinline__ float stage_rows(
    const float* __restrict__ emb_row, short* __restrict__ region,
    int s_begin, int s_end, int khi, int lane)
{
  const float4* emb4 = (const float4*)emb_row;
  float p = 0.f;
  for (int s = s_begin; s < s_end; ++s) {
    const int k0 = 32 * s + 8 * khi;
    float4 fa = make_float4(0.f, 0.f, 0.f, 0.f);
    float4 fb = make_float4(0.f, 0.f, 0.f, 0.f);
    if (k0 < D_EMB)     fa = emb4[k0 >> 2];
    if (k0 + 4 < D_EMB) fb = emb4[(k0 >> 2) + 1];
    unsigned short h[8];
    h[0] = f32_bf16(fa.x); h[1] = f32_bf16(fa.y);
    h[2] = f32_bf16(fa.z); h[3] = f32_bf16(fa.w);
    h[4] = f32_bf16(fb.x); h[5] = f32_bf16(fb.y);
    h[6] = f32_bf16(fb.z); h[7] = f32_bf16(fb.w);
    short8 v;
#pragma unroll
    for (int j = 0; j < 8; ++j) {
      const float x = bf16_f32(h[j]);
      p += x * x;
      v[j] = (short)h[j];
    }
    *(short8*)(region + s * 512 + lane * 8) = v;
  }
  return p;
}

__global__ __launch_bounds__(256) void knrm_main_fb(
    const int* __restrict__ inputs_q, const int* __restrict__ inputs_d,
    const float* __restrict__ mask_d, const float* __restrict__ word_emb,
    float* __restrict__ partial)
{
  const int b    = blockIdx.y;
  const int dt   = blockIdx.x;
  const int tid  = threadIdx.x;
  const int wid  = tid >> 6;
  const int lane = tid & 63;
  const int khi  = lane >> 4;
  const int rl   = lane & 15;

  __shared__ __align__(16) short Afrag[2 * NSTEP * 512];
  __shared__ __align__(16) short Bfrag[4 * NSTEP * 512];
  __shared__ float sumsq_s[96];
  __shared__ float invq_s[LQ], invd_s[DTILE], maskd_s[DTILE];
  __shared__ float red[4][16][NBINS];

  if (tid < 96) sumsq_s[tid] = 0.f;
  if (tid < DTILE) maskd_s[tid] = mask_d[b * LD + dt * DTILE + tid];
  __syncthreads();

  {
    int tok; float p;
    if (wid == 0) {
      tok = inputs_q[b * LQ + rl];
      p = stage_rows(word_emb + (size_t)tok * D_EMB, Afrag, 0, NSTEP, khi, lane);
      p += __shfl_xor(p, 16); p += __shfl_xor(p, 32);
      if (lane < 16) atomicAdd(&sumsq_s[lane], p);
      tok = inputs_d[b * LD + dt * DTILE + rl];
      p = stage_rows(word_emb + (size_t)tok * D_EMB, Bfrag, 0, 5, khi, lane);
      p += __shfl_xor(p, 16); p += __shfl_xor(p, 32);
      if (lane < 16) atomicAdd(&sumsq_s[32 + lane], p);
    } else if (wid == 1) {
      tok = inputs_q[b * LQ + 16 + rl];
      p = stage_rows(word_emb + (size_t)tok * D_EMB, Afrag + NSTEP * 512, 0, NSTEP, khi, lane);
      p += __shfl_xor(p, 16); p += __shfl_xor(p, 32);
      if (lane < 16) atomicAdd(&sumsq_s[16 + lane], p);
      tok = inputs_d[b * LD + dt * DTILE + rl];
      p = stage_rows(word_emb + (size_t)tok * D_EMB, Bfrag, 5, NSTEP, khi, lane);
      p += __shfl_xor(p, 16); p += __shfl_xor(p, 32);
      if (lane < 16) atomicAdd(&sumsq_s[32 + lane], p);
    } else if (wid == 2) {
      tok = inputs_d[b * LD + dt * DTILE + 16 + rl];
      p = stage_rows(word_emb + (size_t)tok * D_EMB, Bfrag + NSTEP * 512, 0, NSTEP, khi, lane);
      p += __shfl_xor(p, 16); p += __shfl_xor(p, 32);
      if (lane < 16) atomicAdd(&sumsq_s[48 + lane], p);
      tok = inputs_d[b * LD + dt * DTILE + 32 + rl];
      p = stage_rows(word_emb + (size_t)tok * D_EMB, Bfrag + 2 * NSTEP * 512, 0, 5, khi, lane);
      p += __shfl_xor(p, 16); p += __shfl_xor(p, 32);
      if (lane < 16) atomicAdd(&sumsq_s[64 + lane], p);
    } else {
      tok = inputs_d[b * LD + dt * DTILE + 48 + rl];
      p = stage_rows(word_emb + (size_t)tok * D_EMB, Bfrag + 3 * NSTEP * 512, 0, NSTEP, khi, lane);
      p += __shfl_xor(p, 16); p += __shfl_xor(p, 32);
      if (lane < 16) atomicAdd(&sumsq_s[80 + lane], p);
      tok = inputs_d[b * LD + dt * DTILE + 32 + rl];
      p = stage_rows(word_emb + (size_t)tok * D_EMB, Bfrag + 2 * NSTEP * 512, 5, NSTEP, khi, lane);
      p += __shfl_xor(p, 16); p += __shfl_xor(p, 32);
      if (lane < 16) atomicAdd(&sumsq_s[64 + lane], p);
    }
  }
  __syncthreads();

  if (tid < 96) {
    const float s   = sumsq_s[tid];
    const float inv = 1.f / fmaxf(sqrtf(s), 1e-12f);
    if (tid < 32) invq_s[tid] = inv; else invd_s[tid - 32] = inv;
  }
  __syncthreads();

  const int qt = wid >> 1, dp = wid & 1;
  const short* Ab = Afrag + qt * NSTEP * 512;
  const short* B0 = Bfrag + (2 * dp) * NSTEP * 512;
  const short* B1 = Bfrag + (2 * dp + 1) * NSTEP * 512;
  floatx4 acc0 = {0.f, 0.f, 0.f, 0.f};
  floatx4 acc1 = {0.f, 0.f, 0.f, 0.f};
#pragma unroll
  for (int s = 0; s < NSTEP; ++s) {
    const short8 a  = *(const short8*)(Ab + s * 512 + lane * 8);
    const short8 b0 = *(const short8*)(B0 + s * 512 + lane * 8);
    const short8 b1 = *(const short8*)(B1 + s * 512 + lane * 8);
    acc0 = __builtin_amdgcn_mfma_f32_16x16x32_bf16(a, b0, acc0, 0, 0, 0);
    acc1 = __builtin_amdgcn_mfma_f32_16x16x32_bf16(a, b1, acc1, 0, 0, 0);
  }

  float ps[4][NBINS];
#pragma unroll
  for (int r = 0; r < 4; ++r)
#pragma unroll
    for (int k = 0; k < NBINS; ++k) ps[r][k] = 0.f;

  float iq[4];
#pragma unroll
  for (int r = 0; r < 4; ++r) iq[r] = invq_s[16 * qt + 4 * khi + r];

#pragma unroll
  for (int t = 0; t < 2; ++t) {
    const int   dl = 32 * dp + 16 * t + rl;
    const float id = invd_s[dl];
    const float md = maskd_s[dl];
    const floatx4 acc = t ? acc1 : acc0;
#pragma unroll
    for (int r = 0; r < 4; ++r) {
      const float sv = acc[r] * iq[r] * id;
#pragma unroll
      for (int k = 0; k < NBINS; ++k) {
        const float d = sv - c_mu[k];
        ps[r][k] += md * __expf(-d * d * c_is2[k]);
      }
    }
  }

#pragma unroll
  for (int off = 1; off < 16; off <<= 1)
#pragma unroll
    for (int r = 0; r < 4; ++r)
#pragma unroll
      for (int k = 0; k < NBINS; ++k)
        ps[r][k] += __shfl_xor(ps[r][k], off);

  if (rl == 0)
#pragma unroll
    for (int r = 0; r < 4; ++r)
#pragma unroll
      for (int k = 0; k < NBINS; ++k)
        red[wid][4 * khi + r][k] = ps[r][k];
  __syncthreads();

  float* pout = partial + ((size_t)dt * BATCH + b) * (LQ * NBINS);
  for (int v = tid; v < LQ * NBINS; v += 256) {
    const int q = v / NBINS, k = v % NBINS;
    pout[v] = (q < 16) ? (red[0][q][k] + red[1][q][k])
                       : (red[2][q - 16][k] + red[3][q - 16][k]);
  }
}

// ---------------------------------------------------------------------------
// Finalize: reduce ndt d-tiles, log, IDF attention weight, sum over q,
// dense+tanh. ndt passed as arg (32 main path / 16 fallback).
__global__ __launch_bounds__(128) void knrm_finalize(
    const float* __restrict__ partial, const int* __restrict__ inputs_q,
    const float* __restrict__ mask_q, const float* __restrict__ attn_table,
    const float* __restrict__ idf_w, const float* __restrict__ idf_b,
    const float* __restrict__ dense_w, const float* __restrict__ dense_b,
    float* __restrict__ out, int ndt)
{
  const int b   = blockIdx.x;
  const int tid = threadIdx.x;
  __shared__ float pool[LQ][NBINS];
  __shared__ float wq_s[LQ];
  __shared__ float lps[NBINS];

  for (int v = tid; v < LQ * NBINS; v += 128) {
    float s = 0.f;
    for (int t = 0; t < ndt; ++t)
      s += partial[((size_t)t * BATCH + b) * (LQ * NBINS) + v];
    pool[v / NBINS][v % NBINS] = logf(fmaxf(s, 1e-10f));
  }
  if (tid < LQ) {
    const int tok = inputs_q[b * LQ + tid];
    wq_s[tid] = mask_q[b * LQ + tid] * (attn_table[tok] * idf_w[0] + idf_b[0]);
  }
  __syncthreads();
  if (tid < NBINS) {
    float s = 0.f;
    for (int q = 0; q < LQ; ++q) s += pool[q][tid] * wq_s[q];
    lps[tid] = 0.01f * s;
  }
  __syncthreads();
  if (tid == 0) {
    float z = dense_b[0];
    for (int k = 0; k < NBINS; ++k) z += lps[k] * dense_w[k];
    out[b] = tanhf(z);
  }
}

extern "C" void kernel_launch(void* const* d_in, const int* in_sizes, int n_in,
                              void* d_out, int out_size, void* d_ws, size_t ws_size,
                              hipStream_t stream) {
  const int*   inputs_q  = (const int*)d_in[0];
  const int*   inputs_d  = (const int*)d_in[1];
  const float* mask_q    = (const float*)d_in[2];
  const float* mask_d    = (const float*)d_in[3];
  const float* word_emb  = (const float*)d_in[4];
  const float* attn_tab  = (const float*)d_in[5];
  const float* idf_w     = (const float*)d_in[6];
  const float* idf_b     = (const float*)d_in[7];
  const float* dense_w   = (const float*)d_in[8];
  const float* dense_b   = (const float*)d_in[9];
  float* out     = (float*)d_out;
  float* partial = (float*)d_ws;

  if (ws_size >= WS_NEED2) {
    unsigned short* qtab = (unsigned short*)((char*)d_ws + QTAB_OFF);
    float* invq          = (float*)((char*)d_ws + INVQ_OFF);
    knrm_qprep<<<BATCH * LQ / 4, 256, 0, stream>>>(inputs_q, word_emb, qtab, invq);
    dim3 grid(NDT2, BATCH);
    knrm_main2<<<grid, 256, 0, stream>>>(inputs_d, mask_d, word_emb, qtab, invq, partial);
    knrm_finalize<<<BATCH, 128, 0, stream>>>(partial, inputs_q, mask_q, attn_tab,
                                             idf_w, idf_b, dense_w, dense_b, out, NDT2);
  } else {
    dim3 grid(NDT, BATCH);
    knrm_main_fb<<<grid, 256, 0, stream>>>(inputs_q, inputs_d, mask_d, word_emb, partial);
    knrm_finalize<<<BATCH, 128, 0, stream>>>(partial, inputs_q, mask_q, attn_tab,
                                             idf_w, idf_b, dense_w, dense_b, out, NDT);
  }
}

// Round 3
// 144.441 us; speedup vs baseline: 1.1336x; 1.1336x over previous
//
#include <hip/hip_runtime.h>
#include <math.h>

#define VOCAB  50000
#define D_EMB  300
#define NBINS  11
#define BATCH  64
#define LQ     32
#define LD     1024
#define NSTEP  10             // K padded to 320 = 10 * 32 (MFMA K=32 steps)
#define DT2    32             // doc tokens per block
#define NDT2   (LD / DT2)     // 32

// workspace: partial [dt][b][q][k] f32 = 2,883,584 B (ws is 256 MiB)
#define PARTIAL2_BYTES ((size_t)NDT2 * BATCH * LQ * NBINS * 4)

typedef __attribute__((ext_vector_type(8))) short short8;   // 8 bf16 (4 VGPRs)
typedef __attribute__((ext_vector_type(4))) float floatx4;  // MFMA C/D

__constant__ float c_mu[NBINS]  = {1.0f, 0.9f, 0.7f, 0.5f, 0.3f, 0.1f,
                                   -0.1f, -0.3f, -0.5f, -0.7f, -0.9f};
// 1 / (2*sigma^2): sigma=1e-3 -> 5e5 ; sigma=0.1 -> 50
__constant__ float c_is2[NBINS] = {500000.0f, 50.f, 50.f, 50.f, 50.f, 50.f,
                                   50.f, 50.f, 50.f, 50.f, 50.f};

static __device__ __forceinline__ unsigned short f32_bf16(float f) {
  unsigned u = __float_as_uint(f);
  u += 0x7FFFu + ((u >> 16) & 1u);          // RNE
  return (unsigned short)(u >> 16);
}
static __device__ __forceinline__ float bf16_f32(unsigned short h) {
  return __uint_as_float(((unsigned)h) << 16);
}

// convert an 8-float slice (two float4) to a bf16 fragment; accumulate
// sum-of-squares of the ROUNDED values (bin-0 exactness).
static __device__ __forceinline__ short8 cvt8(float4 fa, float4 fb, float& p) {
  unsigned short h[8];
  h[0] = f32_bf16(fa.x); h[1] = f32_bf16(fa.y);
  h[2] = f32_bf16(fa.z); h[3] = f32_bf16(fa.w);
  h[4] = f32_bf16(fb.x); h[5] = f32_bf16(fb.y);
  h[6] = f32_bf16(fb.z); h[7] = f32_bf16(fb.w);
  short8 v;
#pragma unroll
  for (int j = 0; j < 8; ++j) {
    const float x = bf16_f32(h[j]);
    p += x * x;
    v[j] = (short)h[j];
  }
  return v;
}

// ---------------------------------------------------------------------------
// Fully register-resident main kernel. One block = (b, 32-doc-token tile),
// 4 waves. Wave (qt=wid>>1, dp=wid&1): lane (khi=lane>>4, rl=lane&15) gathers
// q-row (qt*16+rl) and d-row (dp*16+rl) k-slices khi straight into registers
// (the MFMA A/B fragment layout), converts to bf16 in-register, computes both
// inv-norms via shfl reduces. No staging LDS, no pre-MFMA barrier: all 40
// 16-B loads per thread are independent -> pure TLP latency hiding.
__global__ __launch_bounds__(256) void knrm_main3(
    const int* __restrict__ inputs_q, const int* __restrict__ inputs_d,
    const float* __restrict__ mask_d, const float* __restrict__ word_emb,
    float* __restrict__ partial)
{
  const int b    = blockIdx.y;
  const int dt   = blockIdx.x;                  // 0..31
  const int tid  = threadIdx.x;
  const int wid  = tid >> 6;
  const int lane = tid & 63;
  const int khi  = lane >> 4;   // 0..3
  const int rl   = lane & 15;   // 0..15
  const int qt   = wid >> 1, dp = wid & 1;

  __shared__ float red[4][16][NBINS];           // 2816 B total LDS

  const int dbase = b * LD + dt * DT2;
  const int qtok  = inputs_q[b * LQ + qt * 16 + rl];
  const int dtok  = inputs_d[dbase + dp * 16 + rl];
  const float* qrow = word_emb + (size_t)qtok * D_EMB;
  const float* drow = word_emb + (size_t)dtok * D_EMB;

  short8 afr[NSTEP], bfr[NSTEP];
  float pq = 0.f, pd = 0.f;
#pragma unroll
  for (int s = 0; s < NSTEP; ++s) {
    const int k0 = 32 * s + 8 * khi;            // element offset of this slice
    float4 fa = make_float4(0.f, 0.f, 0.f, 0.f);
    float4 fb = make_float4(0.f, 0.f, 0.f, 0.f);
    if (k0 < D_EMB)     fa = *(const float4*)(qrow + k0);      // 16B aligned
    if (k0 + 4 < D_EMB) fb = *(const float4*)(qrow + k0 + 4);  // zero-pad tail
    afr[s] = cvt8(fa, fb, pq);
  }
#pragma unroll
  for (int s = 0; s < NSTEP; ++s) {
    const int k0 = 32 * s + 8 * khi;
    float4 fa = make_float4(0.f, 0.f, 0.f, 0.f);
    float4 fb = make_float4(0.f, 0.f, 0.f, 0.f);
    if (k0 < D_EMB)     fa = *(const float4*)(drow + k0);
    if (k0 + 4 < D_EMB) fb = *(const float4*)(drow + k0 + 4);
    bfr[s] = cvt8(fa, fb, pd);
  }
  // fold the 4 khi-slices -> per-row sumsq (same tree as the proven kernels)
  pq += __shfl_xor(pq, 16); pq += __shfl_xor(pq, 32);
  pd += __shfl_xor(pd, 16); pd += __shfl_xor(pd, 32);
  const float invq_own = 1.f / fmaxf(sqrtf(pq), 1e-12f);  // row rl of qt half
  const float invd     = 1.f / fmaxf(sqrtf(pd), 1e-12f);  // own C/D column

  floatx4 acc = {0.f, 0.f, 0.f, 0.f};
#pragma unroll
  for (int s = 0; s < NSTEP; ++s)
    acc = __builtin_amdgcn_mfma_f32_16x16x32_bf16(afr[s], bfr[s], acc, 0, 0, 0);

  // C/D row = 4*khi + r -> q-row index; invq held by lane (khi'=0, rl=4khi+r)
  float iq[4];
#pragma unroll
  for (int r = 0; r < 4; ++r) iq[r] = __shfl(invq_own, 4 * khi + r);

  // ---- epilogue: normalize, RBF bins, pool over this wave's 16 d-cols
  const float md = mask_d[dbase + dp * 16 + rl];
  float ps[4][NBINS];
#pragma unroll
  for (int r = 0; r < 4; ++r) {
    const float sv = acc[r] * iq[r] * invd;     // C/D col = rl (own d-row)
#pragma unroll
    for (int k = 0; k < NBINS; ++k) {
      const float d = sv - c_mu[k];
      ps[r][k] = md * __expf(-d * d * c_is2[k]);
    }
  }

#pragma unroll
  for (int off = 1; off < 16; off <<= 1)
#pragma unroll
    for (int r = 0; r < 4; ++r)
#pragma unroll
      for (int k = 0; k < NBINS; ++k)
        ps[r][k] += __shfl_xor(ps[r][k], off);

  if (rl == 0)
#pragma unroll
    for (int r = 0; r < 4; ++r)
#pragma unroll
      for (int k = 0; k < NBINS; ++k)
        red[wid][4 * khi + r][k] = ps[r][k];
  __syncthreads();

  // partial [dt][b][q][k]: contiguous 1408 B per block
  float* pout = partial + ((size_t)dt * BATCH + b) * (LQ * NBINS);
  for (int v = tid; v < LQ * NBINS; v += 256) {
    const int q = v / NBINS, k = v % NBINS;
    pout[v] = (q < 16) ? (red[0][q][k] + red[1][q][k])
                       : (red[2][q - 16][k] + red[3][q - 16][k]);
  }
}

// ---------------------------------------------------------------------------
// Finalize: reduce 32 d-tiles (coalesced across threads per tile), log, IDF
// attention weight, sum over q, dense+tanh.
__global__ __launch_bounds__(128) void knrm_finalize(
    const float* __restrict__ partial, const int* __restrict__ inputs_q,
    const float* __restrict__ mask_q, const float* __restrict__ attn_table,
    const float* __restrict__ idf_w, const float* __restrict__ idf_b,
    const float* __restrict__ dense_w, const float* __restrict__ dense_b,
    float* __restrict__ out)
{
  const int b   = blockIdx.x;
  const int tid = threadIdx.x;
  __shared__ float pool[LQ][NBINS];
  __shared__ float wq_s[LQ];
  __shared__ float lps[NBINS];

  for (int v = tid; v < LQ * NBINS; v += 128) {
    float s = 0.f;
#pragma unroll
    for (int t = 0; t < NDT2; ++t)
      s += partial[((size_t)t * BATCH + b) * (LQ * NBINS) + v];
    pool[v / NBINS][v % NBINS] = logf(fmaxf(s, 1e-10f));
  }
  if (tid < LQ) {
    const int tok = inputs_q[b * LQ + tid];
    wq_s[tid] = mask_q[b * LQ + tid] * (attn_table[tok] * idf_w[0] + idf_b[0]);
  }
  __syncthreads();
  if (tid < NBINS) {
    float s = 0.f;
    for (int q = 0; q < LQ; ++q) s += pool[q][tid] * wq_s[q];
    lps[tid] = 0.01f * s;
  }
  __syncthreads();
  if (tid == 0) {
    float z = dense_b[0];
    for (int k = 0; k < NBINS; ++k) z += lps[k] * dense_w[k];
    out[b] = tanhf(z);
  }
}

extern "C" void kernel_launch(void* const* d_in, const int* in_sizes, int n_in,
                              void* d_out, int out_size, void* d_ws, size_t ws_size,
                              hipStream_t stream) {
  const int*   inputs_q  = (const int*)d_in[0];
  const int*   inputs_d  = (const int*)d_in[1];
  const float* mask_q    = (const float*)d_in[2];
  const float* mask_d    = (const float*)d_in[3];
  const float* word_emb  = (const float*)d_in[4];
  const float* attn_tab  = (const float*)d_in[5];
  const float* idf_w     = (const float*)d_in[6];
  const float* idf_b     = (const float*)d_in[7];
  const float* dense_w   = (const float*)d_in[8];
  const float* dense_b   = (const float*)d_in[9];
  float* out     = (float*)d_out;
  float* partial = (float*)d_ws;   // 2.88 MB of the 256 MiB workspace

  dim3 grid(NDT2, BATCH);
  knrm_main3<<<grid, 256, 0, stream>>>(inputs_q, inputs_d, mask_d, word_emb, partial);
  knrm_finalize<<<BATCH, 128, 0, stream>>>(partial, inputs_q, mask_q, attn_tab,
                                           idf_w, idf_b, dense_w, dense_b, out);
}